// Round 10
// baseline (1013.078 us; speedup 1.0000x reference)
//
#include <hip/hip_runtime.h>
#include <hip/hip_bf16.h>

// MoE MLP (top-2 of 8 experts), D=1024, FF=4096, 8192 tokens, fp32 in/out.
// router(+x->bf16) -> prefix(+tile worklist) -> cvt weights (bf16 [N][K]) ->
// grouped GEMMs. GEMM: 256x256 tile, BK=64, 8 waves (512 thr) each 128x64,
// LDS 128KB double-buffer, global_load_lds with 8-chunk XOR swizzle
// (linear LDS dest + inverse-swizzled global src + swizzled read),
// T3-minimum loop: stage(t+1) -> compute(t) -> vmcnt(0)+barrier (1/tile).

#define N_TOK 8192
#define DMODEL 1024
#define NEXP 8
#define DFF 4096
#define CAP 8192
#define MAXW 72   // >= sum_e ceil(Me/256) = 64 + 8

typedef __attribute__((ext_vector_type(8))) short short8;
typedef __attribute__((ext_vector_type(4))) float f32x4;

#define GLOAD_LDS16(g, l)                                              \
  __builtin_amdgcn_global_load_lds(                                    \
      (const __attribute__((address_space(1))) unsigned int*)(g),      \
      (__attribute__((address_space(3))) unsigned int*)(l), 16, 0, 0)

__device__ __forceinline__ unsigned short f2bf(float f) {
  unsigned u = __float_as_uint(f);
  return (unsigned short)((u + 0x7FFFu + ((u >> 16) & 1u)) >> 16);  // RNE
}

__device__ __forceinline__ float gelu_f(float v) {
  return 0.5f * v * (1.0f + erff(v * 0.70710678118654752f));
}

// ---------------- Router: 1 wave per token (+ x -> bf16 copy) ----------------
__global__ void router_k(const float* __restrict__ x, const float* __restrict__ rw,
                         int* __restrict__ cnt, int* __restrict__ tok,
                         float* __restrict__ gate, unsigned short* __restrict__ xb) {
  int lane = threadIdx.x & 63;
  int t = blockIdx.x * 4 + (threadIdx.x >> 6);
  const float* xr = x + (size_t)t * DMODEL;
  unsigned short* xbr = xb + (size_t)t * DMODEL;
  float p[8];
#pragma unroll
  for (int e = 0; e < 8; ++e) p[e] = 0.0f;
#pragma unroll
  for (int j = 0; j < DMODEL / 64; ++j) {
    int i = lane + j * 64;
    float xv = xr[i];
    xbr[i] = f2bf(xv);
    const float4* r = (const float4*)(rw + (size_t)i * 8);
    float4 a = r[0], b = r[1];
    p[0] += xv * a.x; p[1] += xv * a.y; p[2] += xv * a.z; p[3] += xv * a.w;
    p[4] += xv * b.x; p[5] += xv * b.y; p[6] += xv * b.z; p[7] += xv * b.w;
  }
#pragma unroll
  for (int e = 0; e < 8; ++e) {
#pragma unroll
    for (int off = 32; off; off >>= 1) p[e] += __shfl_xor(p[e], off, 64);
  }
  if (lane == 0) {
    int e1 = 0;
#pragma unroll
    for (int e = 1; e < 8; ++e) if (p[e] > p[e1]) e1 = e;
    int e2 = (e1 == 0) ? 1 : 0;
#pragma unroll
    for (int e = 0; e < 8; ++e) if (e != e1 && p[e] > p[e2]) e2 = e;
    float w1 = 1.0f / (1.0f + expf(p[e2] - p[e1]));
    float w2 = 1.0f - w1;
    int s1 = atomicAdd(&cnt[e1], 1);
    tok[e1 * CAP + s1] = t; gate[e1 * CAP + s1] = w1;
    int s2 = atomicAdd(&cnt[e2], 1);
    tok[e2 * CAP + s2] = t; gate[e2 * CAP + s2] = w2;
  }
}

// prefix sums + compact worklist of (expert, 256-row m-tile) pairs
__global__ void prefix_k(const int* __restrict__ cnt, int* __restrict__ off,
                         int* __restrict__ nwork, int* __restrict__ wl) {
  if (threadIdx.x == 0 && blockIdx.x == 0) {
    int s = 0, n = 0;
    for (int e = 0; e < NEXP; ++e) {
      off[e] = s;
      int ntile = (cnt[e] + 255) >> 8;
      for (int mt = 0; mt < ntile; ++mt) wl[n++] = (e << 16) | mt;
      s += cnt[e];
    }
    nwork[0] = n;
  }
}

// W [E][K][N] fp32 -> WT [E][N][K] bf16 (64x64 tile LDS transpose)
__global__ __launch_bounds__(256) void cvt_wt_k(const float* __restrict__ W,
                                                unsigned short* __restrict__ WT,
                                                int K, int N) {
  __shared__ float ls[64][68];
  int b = blockIdx.x;
  int nkt = K >> 6, nnt = N >> 6;
  int kt = b % nkt;
  int nt = (b / nkt) % nnt;
  int e = b / (nkt * nnt);
  const float* Wb = W + (size_t)e * K * N + (size_t)(kt * 64) * N + nt * 64;
  int t = threadIdx.x;
  int nn = (t & 15) * 4, kr = t >> 4;
#pragma unroll
  for (int i = 0; i < 4; ++i) {
    float4 v = *(const float4*)(Wb + (size_t)(kr + 16 * i) * N + nn);
    *(float4*)&ls[kr + 16 * i][nn] = v;
  }
  __syncthreads();
  int on = t >> 2, kc = (t & 3) * 16;
  unsigned short* dst = WT + (size_t)e * N * K + (size_t)(nt * 64 + on) * K + kt * 64 + kc;
  short8 r0, r1;
#pragma unroll
  for (int j = 0; j < 8; ++j) r0[j] = (short)f2bf(ls[kc + j][on]);
#pragma unroll
  for (int j = 0; j < 8; ++j) r1[j] = (short)f2bf(ls[kc + 8 + j][on]);
  *(short8*)dst = r0;
  *(short8*)(dst + 8) = r1;
}

// ---- 256x256/BK64 GEMM core ----
// Staging: thread t -> physical 16B-chunk pc = t&7, rows (t>>3)+{0,64,128,192}
// of the 256-row tile. LDS dest = row*64 + pc*8 shorts (per wave: uniform base
// + lane*16B). Global src k-offset pre-XORed: logical chunk = pc ^ (row&7).
// Read: logical chunk c=(kk*4+g) at row -> physical c^(row&7); row&7 == fr&7.
#define STAGE(buf, kt)                                                  \
  do {                                                                  \
    int kk_ = (kt) * 64;                                                \
    GLOAD_LDS16(gA0 + kk_, &As[buf][dL0]);                              \
    GLOAD_LDS16(gA1 + kk_, &As[buf][dL1]);                              \
    GLOAD_LDS16(gA2 + kk_, &As[buf][dL2]);                              \
    GLOAD_LDS16(gA3 + kk_, &As[buf][dL3]);                              \
    GLOAD_LDS16(gB0 + kk_, &Bs[buf][dL0]);                              \
    GLOAD_LDS16(gB1 + kk_, &Bs[buf][dL1]);                              \
    GLOAD_LDS16(gB2 + kk_, &Bs[buf][dL2]);                              \
    GLOAD_LDS16(gB3 + kk_, &Bs[buf][dL3]);                              \
  } while (0)

#define COMPUTE(buf)                                                             \
  do {                                                                           \
    __builtin_amdgcn_s_setprio(1);                                               \
    _Pragma("unroll") for (int kk = 0; kk < 2; ++kk) {                           \
      int co = kk ? co1 : co0;                                                   \
      short8 af[8], bfv[4];                                                      \
      _Pragma("unroll") for (int mi = 0; mi < 8; ++mi)                           \
          af[mi] = *(const short8*)&As[buf][(wr * 128 + mi * 16 + fr) * 64 + co];\
      _Pragma("unroll") for (int ni = 0; ni < 4; ++ni)                           \
          bfv[ni] = *(const short8*)&Bs[buf][(wc * 64 + ni * 16 + fr) * 64 + co];\
      _Pragma("unroll") for (int mi = 0; mi < 8; ++mi)                           \
          _Pragma("unroll") for (int ni = 0; ni < 4; ++ni)                       \
              acc[mi][ni] = __builtin_amdgcn_mfma_f32_16x16x32_bf16(             \
                  af[mi], bfv[ni], acc[mi][ni], 0, 0, 0);                        \
    }                                                                            \
    __builtin_amdgcn_s_setprio(0);                                               \
  } while (0)

#define VMCNT0() asm volatile("s_waitcnt vmcnt(0)" ::: "memory")
#define BAR() __builtin_amdgcn_s_barrier()

// T3-minimum: stage(t+1) issued first, long compute covers latency, ONE
// vmcnt(0)+barrier per K-tile. NT even (16 / 64) -> static buf indices.
#define KLOOP(NT_)                                                  \
  STAGE(0, 0);                                                      \
  VMCNT0(); BAR();                                                  \
  _Pragma("unroll 1") for (int t = 0; t + 2 < (NT_); t += 2) {      \
    STAGE(1, t + 1); COMPUTE(0); VMCNT0(); BAR();                   \
    STAGE(0, t + 2); COMPUTE(1); VMCNT0(); BAR();                   \
  }                                                                 \
  STAGE(1, (NT_)-1); COMPUTE(0); VMCNT0(); BAR();                   \
  COMPUTE(1);

// ---------------- GEMM1: h = gelu(Xb_gathered @ wfcT + bfc) ----------------
#define NT1 16
__global__ __launch_bounds__(512, 1) void gemm1a_k(
    const unsigned short* __restrict__ xb, const unsigned short* __restrict__ wT,
    const float* __restrict__ bfc, const int* __restrict__ cnt,
    const int* __restrict__ off, const int* __restrict__ tok,
    const int* __restrict__ nwork, const int* __restrict__ wl,
    unsigned short* __restrict__ h) {
  int bid = (int)(blockIdx.x & 7) * ((int)gridDim.x >> 3) + (int)(blockIdx.x >> 3);
  int widx = bid % MAXW;  // fast: same-expert runs share the B-slab in L2
  int nt = bid / MAXW;
  if (widx >= nwork[0]) return;
  int wle = wl[widx];
  int e = wle >> 16;
  int mt = wle & 0xffff;
  int Me = cnt[e];
  int base = off[e];
  int n0 = nt * 256;

  __shared__ __align__(16) unsigned short As[2][256 * 64];
  __shared__ __align__(16) unsigned short Bs[2][256 * 64];

  int tid = threadIdx.x;
  int lane = tid & 63, w = tid >> 6;
  int srow = tid >> 3;                        // 0..63
  int lcsw = (((tid & 7) ^ (srow & 7)) * 8);  // swizzled global k-offset (shorts)
  int dL0 = srow * 64 + (tid & 7) * 8;        // linear LDS dest (shorts)
  int dL1 = dL0 + 64 * 64, dL2 = dL0 + 128 * 64, dL3 = dL0 + 192 * 64;

  int a0 = mt * 256 + srow;
  int t0 = tok[e * CAP + ((a0 < Me) ? a0 : (Me - 1))];
  int t1 = tok[e * CAP + ((a0 + 64 < Me) ? a0 + 64 : (Me - 1))];
  int t2 = tok[e * CAP + ((a0 + 128 < Me) ? a0 + 128 : (Me - 1))];
  int t3 = tok[e * CAP + ((a0 + 192 < Me) ? a0 + 192 : (Me - 1))];
  const unsigned short* gA0 = xb + (size_t)t0 * DMODEL + lcsw;
  const unsigned short* gA1 = xb + (size_t)t1 * DMODEL + lcsw;
  const unsigned short* gA2 = xb + (size_t)t2 * DMODEL + lcsw;
  const unsigned short* gA3 = xb + (size_t)t3 * DMODEL + lcsw;
  const unsigned short* gB0 = wT + ((size_t)e * DFF + n0 + srow) * DMODEL + lcsw;
  const unsigned short* gB1 = gB0 + (size_t)64 * DMODEL;
  const unsigned short* gB2 = gB0 + (size_t)128 * DMODEL;
  const unsigned short* gB3 = gB0 + (size_t)192 * DMODEL;

  int wr = w >> 2, wc = w & 3;
  int g = lane >> 4, fr = lane & 15;
  int co0 = ((g ^ (fr & 7)) * 8);
  int co1 = (((4 + g) ^ (fr & 7)) * 8);

  f32x4 acc[8][4];
#pragma unroll
  for (int i = 0; i < 8; ++i)
#pragma unroll
    for (int j = 0; j < 4; ++j) acc[i][j] = (f32x4)0.0f;

  KLOOP(NT1);

#pragma unroll
  for (int mi = 0; mi < 8; ++mi) {
    int rl = wr * 128 + mi * 16 + g * 4;
#pragma unroll
    for (int i = 0; i < 4; ++i) {
      int r = mt * 256 + rl + i;
      if (r < Me) {
        unsigned short* hrow = h + (size_t)(base + r) * DFF;
#pragma unroll
        for (int ni = 0; ni < 4; ++ni) {
          int col = n0 + wc * 64 + ni * 16 + fr;
          float v = acc[mi][ni][i] + bfc[e * DFF + col];
          hrow[col] = f2bf(gelu_f(v));
        }
      }
    }
  }
}

// ---------------- GEMM2: out += gate * (h @ wprojT + bproj) ----------------
#define NT2 4
__global__ __launch_bounds__(512, 1) void gemm2a_k(
    const unsigned short* __restrict__ h, const unsigned short* __restrict__ wT,
    const float* __restrict__ bproj, const int* __restrict__ cnt,
    const int* __restrict__ off, const int* __restrict__ tok,
    const int* __restrict__ nwork, const int* __restrict__ wl,
    const float* __restrict__ gate, float* __restrict__ out) {
  int bid = (int)(blockIdx.x & 7) * ((int)gridDim.x >> 3) + (int)(blockIdx.x >> 3);
  int widx = bid % MAXW;
  int nt = bid / MAXW;
  if (widx >= nwork[0]) return;
  int wle = wl[widx];
  int e = wle >> 16;
  int mt = wle & 0xffff;
  int Me = cnt[e];
  int base = off[e];
  int n0 = nt * 256;

  __shared__ __align__(16) unsigned short As[2][256 * 64];
  __shared__ __align__(16) unsigned short Bs[2][256 * 64];

  int tid = threadIdx.x;
  int lane = tid & 63, w = tid >> 6;
  int srow = tid >> 3;
  int lcsw = (((tid & 7) ^ (srow & 7)) * 8);
  int dL0 = srow * 64 + (tid & 7) * 8;
  int dL1 = dL0 + 64 * 64, dL2 = dL0 + 128 * 64, dL3 = dL0 + 192 * 64;

  // A rows beyond Me read following rows (in-bounds: h padded +256); masked at store.
  const unsigned short* gA0 = h + (size_t)(base + mt * 256 + srow) * DFF + lcsw;
  const unsigned short* gA1 = gA0 + (size_t)64 * DFF;
  const unsigned short* gA2 = gA0 + (size_t)128 * DFF;
  const unsigned short* gA3 = gA0 + (size_t)192 * DFF;
  const unsigned short* gB0 = wT + ((size_t)e * DMODEL + n0 + srow) * DFF + lcsw;
  const unsigned short* gB1 = gB0 + (size_t)64 * DFF;
  const unsigned short* gB2 = gB0 + (size_t)128 * DFF;
  const unsigned short* gB3 = gB0 + (size_t)192 * DFF;

  int wr = w >> 2, wc = w & 3;
  int g = lane >> 4, fr = lane & 15;
  int co0 = ((g ^ (fr & 7)) * 8);
  int co1 = (((4 + g) ^ (fr & 7)) * 8);

  f32x4 acc[8][4];
#pragma unroll
  for (int i = 0; i < 8; ++i)
#pragma unroll
    for (int j = 0; j < 4; ++j) acc[i][j] = (f32x4)0.0f;

  KLOOP(64);

#pragma unroll
  for (int mi = 0; mi < 8; ++mi) {
    int rl = wr * 128 + mi * 16 + g * 4;
#pragma unroll
    for (int i = 0; i < 4; ++i) {
      int r = mt * 256 + rl + i;
      if (r < Me) {
        int tkn = tok[e * CAP + r];
        float gv = gate[e * CAP + r];
        float* orow = out + (size_t)tkn * DMODEL;
#pragma unroll
        for (int ni = 0; ni < 4; ++ni) {
          int col = n0 + wc * 64 + ni * 16 + fr;
          float v = acc[mi][ni][i] + bproj[e * DMODEL + col];
          atomicAdd(orow + col, gv * v);
        }
      }
    }
  }
}

extern "C" void kernel_launch(void* const* d_in, const int* in_sizes, int n_in,
                              void* d_out, int out_size, void* d_ws, size_t ws_size,
                              hipStream_t stream) {
  const float* x = (const float*)d_in[0];
  const float* rw = (const float*)d_in[1];
  const float* wfc = (const float*)d_in[2];
  const float* bfc = (const float*)d_in[3];
  const float* wproj = (const float*)d_in[4];
  const float* bproj = (const float*)d_in[5];
  float* out = (float*)d_out;

  char* ws = (char*)d_ws;
  int* cnt = (int*)ws;
  int* off_ = (int*)(ws + 64);
  int* nwork = (int*)(ws + 128);
  int* wl = (int*)(ws + 256);              // <= 72 ints
  int* tok = (int*)(ws + 4096);
  float* gate = (float*)(ws + 4096 + (size_t)NEXP * CAP * 4);
  size_t HOFF = 4096 + 2 * (size_t)NEXP * CAP * 4;
  unsigned short* h = (unsigned short*)(ws + HOFF);
  size_t HSZ = (size_t)(16384 + 256) * DFF * 2;
  size_t XOFF = HOFF + HSZ;
  size_t WOFF = XOFF + (size_t)N_TOK * DMODEL * 2;
  size_t WSZ = (size_t)NEXP * DFF * DMODEL * 2;  // 64MB
  unsigned short* xb = (unsigned short*)(ws + XOFF);
  unsigned short* wT1 = (unsigned short*)(ws + WOFF);

  hipMemsetAsync(cnt, 0, 128, stream);
  hipMemsetAsync(out, 0, (size_t)out_size * 4, stream);
  router_k<<<N_TOK / 4, 256, 0, stream>>>(x, rw, cnt, tok, gate, xb);
  prefix_k<<<1, 64, 0, stream>>>(cnt, off_, nwork, wl);

  if (ws_size >= WOFF + 2 * WSZ) {
    unsigned short* wT2 = (unsigned short*)(ws + WOFF + WSZ);
    cvt_wt_k<<<NEXP * (DMODEL / 64) * (DFF / 64), 256, 0, stream>>>(wfc, wT1, DMODEL, DFF);
    cvt_wt_k<<<NEXP * (DFF / 64) * (DMODEL / 64), 256, 0, stream>>>(wproj, wT2, DFF, DMODEL);
    gemm1a_k<<<MAXW * NT1, 512, 0, stream>>>(xb, wT1, bfc, cnt, off_, tok, nwork, wl, h);
    gemm2a_k<<<MAXW * NT2, 512, 0, stream>>>(h, wT2, bproj, cnt, off_, tok, nwork, wl, gate, out);
  } else {
    cvt_wt_k<<<NEXP * (DMODEL / 64) * (DFF / 64), 256, 0, stream>>>(wfc, wT1, DMODEL, DFF);
    gemm1a_k<<<MAXW * NT1, 512, 0, stream>>>(xb, wT1, bfc, cnt, off_, tok, nwork, wl, h);
    cvt_wt_k<<<NEXP * (DFF / 64) * (DMODEL / 64), 256, 0, stream>>>(wproj, wT1, DFF, DMODEL);
    gemm2a_k<<<MAXW * NT2, 512, 0, stream>>>(h, wT1, bproj, cnt, off_, tok, nwork, wl, gate, out);
  }
}

// Round 11
// 1005.237 us; speedup vs baseline: 1.0078x; 1.0078x over previous
//
#include <hip/hip_runtime.h>
#include <hip/hip_bf16.h>

// MoE MLP (top-2 of 8 experts), D=1024, FF=4096, 8192 tokens, fp32 in/out.
// router(+x->bf16) -> prefix(+tile worklist) -> cvt weights (bf16 [N][K]) ->
// grouped GEMMs. GEMM: 256x256 tile, BK=64, 8 waves (512 thr) each 128x64,
// LDS 128KB double-buffer, global_load_lds with 8-chunk XOR swizzle
// (linear LDS dest + inverse-swizzled global src + swizzled read; verified
// 0 bank conflicts in R10). K-loop: counted vmcnt(8), 2-tile lookahead --
// never drains to 0 in the main loop (fixes R10's per-tile drain stall).

#define N_TOK 8192
#define DMODEL 1024
#define NEXP 8
#define DFF 4096
#define CAP 8192
#define MAXW 72   // >= sum_e ceil(Me/256) = 64 + 8

typedef __attribute__((ext_vector_type(8))) short short8;
typedef __attribute__((ext_vector_type(4))) float f32x4;

#define GLOAD_LDS16(g, l)                                              \
  __builtin_amdgcn_global_load_lds(                                    \
      (const __attribute__((address_space(1))) unsigned int*)(g),      \
      (__attribute__((address_space(3))) unsigned int*)(l), 16, 0, 0)

__device__ __forceinline__ unsigned short f2bf(float f) {
  unsigned u = __float_as_uint(f);
  return (unsigned short)((u + 0x7FFFu + ((u >> 16) & 1u)) >> 16);  // RNE
}

__device__ __forceinline__ float gelu_f(float v) {
  return 0.5f * v * (1.0f + erff(v * 0.70710678118654752f));
}

// ---------------- Router: 1 wave per token (+ x -> bf16 copy) ----------------
__global__ void router_k(const float* __restrict__ x, const float* __restrict__ rw,
                         int* __restrict__ cnt, int* __restrict__ tok,
                         float* __restrict__ gate, unsigned short* __restrict__ xb) {
  int lane = threadIdx.x & 63;
  int t = blockIdx.x * 4 + (threadIdx.x >> 6);
  const float* xr = x + (size_t)t * DMODEL;
  unsigned short* xbr = xb + (size_t)t * DMODEL;
  float p[8];
#pragma unroll
  for (int e = 0; e < 8; ++e) p[e] = 0.0f;
#pragma unroll
  for (int j = 0; j < DMODEL / 64; ++j) {
    int i = lane + j * 64;
    float xv = xr[i];
    xbr[i] = f2bf(xv);
    const float4* r = (const float4*)(rw + (size_t)i * 8);
    float4 a = r[0], b = r[1];
    p[0] += xv * a.x; p[1] += xv * a.y; p[2] += xv * a.z; p[3] += xv * a.w;
    p[4] += xv * b.x; p[5] += xv * b.y; p[6] += xv * b.z; p[7] += xv * b.w;
  }
#pragma unroll
  for (int e = 0; e < 8; ++e) {
#pragma unroll
    for (int off = 32; off; off >>= 1) p[e] += __shfl_xor(p[e], off, 64);
  }
  if (lane == 0) {
    int e1 = 0;
#pragma unroll
    for (int e = 1; e < 8; ++e) if (p[e] > p[e1]) e1 = e;
    int e2 = (e1 == 0) ? 1 : 0;
#pragma unroll
    for (int e = 0; e < 8; ++e) if (e != e1 && p[e] > p[e2]) e2 = e;
    float w1 = 1.0f / (1.0f + expf(p[e2] - p[e1]));
    float w2 = 1.0f - w1;
    int s1 = atomicAdd(&cnt[e1], 1);
    tok[e1 * CAP + s1] = t; gate[e1 * CAP + s1] = w1;
    int s2 = atomicAdd(&cnt[e2], 1);
    tok[e2 * CAP + s2] = t; gate[e2 * CAP + s2] = w2;
  }
}

// prefix sums + compact worklist of (expert, 256-row m-tile) pairs
__global__ void prefix_k(const int* __restrict__ cnt, int* __restrict__ off,
                         int* __restrict__ nwork, int* __restrict__ wl) {
  if (threadIdx.x == 0 && blockIdx.x == 0) {
    int s = 0, n = 0;
    for (int e = 0; e < NEXP; ++e) {
      off[e] = s;
      int ntile = (cnt[e] + 255) >> 8;
      for (int mt = 0; mt < ntile; ++mt) wl[n++] = (e << 16) | mt;
      s += cnt[e];
    }
    nwork[0] = n;
  }
}

// W [E][K][N] fp32 -> WT [E][N][K] bf16 (64x64 tile LDS transpose)
__global__ __launch_bounds__(256) void cvt_wt_k(const float* __restrict__ W,
                                                unsigned short* __restrict__ WT,
                                                int K, int N) {
  __shared__ float ls[64][68];
  int b = blockIdx.x;
  int nkt = K >> 6, nnt = N >> 6;
  int kt = b % nkt;
  int nt = (b / nkt) % nnt;
  int e = b / (nkt * nnt);
  const float* Wb = W + (size_t)e * K * N + (size_t)(kt * 64) * N + nt * 64;
  int t = threadIdx.x;
  int nn = (t & 15) * 4, kr = t >> 4;
#pragma unroll
  for (int i = 0; i < 4; ++i) {
    float4 v = *(const float4*)(Wb + (size_t)(kr + 16 * i) * N + nn);
    *(float4*)&ls[kr + 16 * i][nn] = v;
  }
  __syncthreads();
  int on = t >> 2, kc = (t & 3) * 16;
  unsigned short* dst = WT + (size_t)e * N * K + (size_t)(nt * 64 + on) * K + kt * 64 + kc;
  short8 r0, r1;
#pragma unroll
  for (int j = 0; j < 8; ++j) r0[j] = (short)f2bf(ls[kc + j][on]);
#pragma unroll
  for (int j = 0; j < 8; ++j) r1[j] = (short)f2bf(ls[kc + 8 + j][on]);
  *(short8*)dst = r0;
  *(short8*)(dst + 8) = r1;
}

// ---- 256x256/BK64 GEMM core (R10 geometry + swizzle, verified 0 conflicts) ----
#define STAGE(buf, kt)                                                  \
  do {                                                                  \
    int kk_ = (kt) * 64;                                                \
    GLOAD_LDS16(gA0 + kk_, &As[buf][dL0]);                              \
    GLOAD_LDS16(gA1 + kk_, &As[buf][dL1]);                              \
    GLOAD_LDS16(gA2 + kk_, &As[buf][dL2]);                              \
    GLOAD_LDS16(gA3 + kk_, &As[buf][dL3]);                              \
    GLOAD_LDS16(gB0 + kk_, &Bs[buf][dL0]);                              \
    GLOAD_LDS16(gB1 + kk_, &Bs[buf][dL1]);                              \
    GLOAD_LDS16(gB2 + kk_, &Bs[buf][dL2]);                              \
    GLOAD_LDS16(gB3 + kk_, &Bs[buf][dL3]);                              \
  } while (0)

#define COMPUTE(buf)                                                             \
  do {                                                                           \
    __builtin_amdgcn_s_setprio(1);                                               \
    _Pragma("unroll") for (int kk = 0; kk < 2; ++kk) {                           \
      int co = kk ? co1 : co0;                                                   \
      short8 af[8], bfv[4];                                                      \
      _Pragma("unroll") for (int mi = 0; mi < 8; ++mi)                           \
          af[mi] = *(const short8*)&As[buf][(wr * 128 + mi * 16 + fr) * 64 + co];\
      _Pragma("unroll") for (int ni = 0; ni < 4; ++ni)                           \
          bfv[ni] = *(const short8*)&Bs[buf][(wc * 64 + ni * 16 + fr) * 64 + co];\
      _Pragma("unroll") for (int mi = 0; mi < 8; ++mi)                           \
          _Pragma("unroll") for (int ni = 0; ni < 4; ++ni)                       \
              acc[mi][ni] = __builtin_amdgcn_mfma_f32_16x16x32_bf16(             \
                  af[mi], bfv[ni], acc[mi][ni], 0, 0, 0);                        \
    }                                                                            \
    __builtin_amdgcn_s_setprio(0);                                               \
  } while (0)

#define WAITV(n) asm volatile("s_waitcnt vmcnt(" #n ")" ::: "memory")
#define BAR() __builtin_amdgcn_s_barrier()

// Counted-vmcnt 2-tile lookahead: 16 loads/thread in flight at steady state;
// WAITV(8) retires only the current tile -- never drains to 0 in the loop.
// Each staged tile gets a full 64-MFMA compute phase + 2 barriers of cover.
// NT even (16 / 64) -> static buffer indices.
#define KLOOP(NT_)                                                  \
  STAGE(0, 0);                                                      \
  STAGE(1, 1);                                                      \
  _Pragma("unroll 1") for (int t = 0; t + 2 < (NT_); t += 2) {      \
    WAITV(8); BAR(); COMPUTE(0); BAR(); STAGE(0, t + 2);            \
    WAITV(8); BAR(); COMPUTE(1); BAR(); STAGE(1, t + 3);            \
  }                                                                 \
  WAITV(8); BAR(); COMPUTE(0);                                      \
  WAITV(0); BAR(); COMPUTE(1);

// ---------------- GEMM1: h = gelu(Xb_gathered @ wfcT + bfc) ----------------
#define NT1 16
__global__ __launch_bounds__(512, 1) void gemm1a_k(
    const unsigned short* __restrict__ xb, const unsigned short* __restrict__ wT,
    const float* __restrict__ bfc, const int* __restrict__ cnt,
    const int* __restrict__ off, const int* __restrict__ tok,
    const int* __restrict__ nwork, const int* __restrict__ wl,
    unsigned short* __restrict__ h) {
  int bid = (int)(blockIdx.x & 7) * ((int)gridDim.x >> 3) + (int)(blockIdx.x >> 3);
  int widx = bid % MAXW;  // fast: same-expert runs share the B-slab in L2
  int nt = bid / MAXW;
  if (widx >= nwork[0]) return;
  int wle = wl[widx];
  int e = wle >> 16;
  int mt = wle & 0xffff;
  int Me = cnt[e];
  int base = off[e];
  int n0 = nt * 256;

  __shared__ __align__(16) unsigned short As[2][256 * 64];
  __shared__ __align__(16) unsigned short Bs[2][256 * 64];

  int tid = threadIdx.x;
  int lane = tid & 63, w = tid >> 6;
  int srow = tid >> 3;                        // 0..63
  int lcsw = (((tid & 7) ^ (srow & 7)) * 8);  // swizzled global k-offset (shorts)
  int dL0 = srow * 64 + (tid & 7) * 8;        // linear LDS dest (shorts)
  int dL1 = dL0 + 64 * 64, dL2 = dL0 + 128 * 64, dL3 = dL0 + 192 * 64;

  int a0 = mt * 256 + srow;
  int t0 = tok[e * CAP + ((a0 < Me) ? a0 : (Me - 1))];
  int t1 = tok[e * CAP + ((a0 + 64 < Me) ? a0 + 64 : (Me - 1))];
  int t2 = tok[e * CAP + ((a0 + 128 < Me) ? a0 + 128 : (Me - 1))];
  int t3 = tok[e * CAP + ((a0 + 192 < Me) ? a0 + 192 : (Me - 1))];
  const unsigned short* gA0 = xb + (size_t)t0 * DMODEL + lcsw;
  const unsigned short* gA1 = xb + (size_t)t1 * DMODEL + lcsw;
  const unsigned short* gA2 = xb + (size_t)t2 * DMODEL + lcsw;
  const unsigned short* gA3 = xb + (size_t)t3 * DMODEL + lcsw;
  const unsigned short* gB0 = wT + ((size_t)e * DFF + n0 + srow) * DMODEL + lcsw;
  const unsigned short* gB1 = gB0 + (size_t)64 * DMODEL;
  const unsigned short* gB2 = gB0 + (size_t)128 * DMODEL;
  const unsigned short* gB3 = gB0 + (size_t)192 * DMODEL;

  int wr = w >> 2, wc = w & 3;
  int g = lane >> 4, fr = lane & 15;
  int co0 = ((g ^ (fr & 7)) * 8);
  int co1 = (((4 + g) ^ (fr & 7)) * 8);

  f32x4 acc[8][4];
#pragma unroll
  for (int i = 0; i < 8; ++i)
#pragma unroll
    for (int j = 0; j < 4; ++j) acc[i][j] = (f32x4)0.0f;

  KLOOP(NT1);

#pragma unroll
  for (int mi = 0; mi < 8; ++mi) {
    int rl = wr * 128 + mi * 16 + g * 4;
#pragma unroll
    for (int i = 0; i < 4; ++i) {
      int r = mt * 256 + rl + i;
      if (r < Me) {
        unsigned short* hrow = h + (size_t)(base + r) * DFF;
#pragma unroll
        for (int ni = 0; ni < 4; ++ni) {
          int col = n0 + wc * 64 + ni * 16 + fr;
          float v = acc[mi][ni][i] + bfc[e * DFF + col];
          hrow[col] = f2bf(gelu_f(v));
        }
      }
    }
  }
}

// ---------------- GEMM2: out += gate * (h @ wprojT + bproj) ----------------
#define NT2 4
__global__ __launch_bounds__(512, 1) void gemm2a_k(
    const unsigned short* __restrict__ h, const unsigned short* __restrict__ wT,
    const float* __restrict__ bproj, const int* __restrict__ cnt,
    const int* __restrict__ off, const int* __restrict__ tok,
    const int* __restrict__ nwork, const int* __restrict__ wl,
    const float* __restrict__ gate, float* __restrict__ out) {
  int bid = (int)(blockIdx.x & 7) * ((int)gridDim.x >> 3) + (int)(blockIdx.x >> 3);
  int widx = bid % MAXW;
  int nt = bid / MAXW;
  if (widx >= nwork[0]) return;
  int wle = wl[widx];
  int e = wle >> 16;
  int mt = wle & 0xffff;
  int Me = cnt[e];
  int base = off[e];
  int n0 = nt * 256;

  __shared__ __align__(16) unsigned short As[2][256 * 64];
  __shared__ __align__(16) unsigned short Bs[2][256 * 64];

  int tid = threadIdx.x;
  int lane = tid & 63, w = tid >> 6;
  int srow = tid >> 3;
  int lcsw = (((tid & 7) ^ (srow & 7)) * 8);
  int dL0 = srow * 64 + (tid & 7) * 8;
  int dL1 = dL0 + 64 * 64, dL2 = dL0 + 128 * 64, dL3 = dL0 + 192 * 64;

  // A rows beyond Me read following rows (in-bounds: h padded +256); masked at store.
  const unsigned short* gA0 = h + (size_t)(base + mt * 256 + srow) * DFF + lcsw;
  const unsigned short* gA1 = gA0 + (size_t)64 * DFF;
  const unsigned short* gA2 = gA0 + (size_t)128 * DFF;
  const unsigned short* gA3 = gA0 + (size_t)192 * DFF;
  const unsigned short* gB0 = wT + ((size_t)e * DMODEL + n0 + srow) * DFF + lcsw;
  const unsigned short* gB1 = gB0 + (size_t)64 * DFF;
  const unsigned short* gB2 = gB0 + (size_t)128 * DFF;
  const unsigned short* gB3 = gB0 + (size_t)192 * DFF;

  int wr = w >> 2, wc = w & 3;
  int g = lane >> 4, fr = lane & 15;
  int co0 = ((g ^ (fr & 7)) * 8);
  int co1 = (((4 + g) ^ (fr & 7)) * 8);

  f32x4 acc[8][4];
#pragma unroll
  for (int i = 0; i < 8; ++i)
#pragma unroll
    for (int j = 0; j < 4; ++j) acc[i][j] = (f32x4)0.0f;

  KLOOP(64);

#pragma unroll
  for (int mi = 0; mi < 8; ++mi) {
    int rl = wr * 128 + mi * 16 + g * 4;
#pragma unroll
    for (int i = 0; i < 4; ++i) {
      int r = mt * 256 + rl + i;
      if (r < Me) {
        int tkn = tok[e * CAP + r];
        float gv = gate[e * CAP + r];
        float* orow = out + (size_t)tkn * DMODEL;
#pragma unroll
        for (int ni = 0; ni < 4; ++ni) {
          int col = n0 + wc * 64 + ni * 16 + fr;
          float v = acc[mi][ni][i] + bproj[e * DMODEL + col];
          atomicAdd(orow + col, gv * v);
        }
      }
    }
  }
}

extern "C" void kernel_launch(void* const* d_in, const int* in_sizes, int n_in,
                              void* d_out, int out_size, void* d_ws, size_t ws_size,
                              hipStream_t stream) {
  const float* x = (const float*)d_in[0];
  const float* rw = (const float*)d_in[1];
  const float* wfc = (const float*)d_in[2];
  const float* bfc = (const float*)d_in[3];
  const float* wproj = (const float*)d_in[4];
  const float* bproj = (const float*)d_in[5];
  float* out = (float*)d_out;

  char* ws = (char*)d_ws;
  int* cnt = (int*)ws;
  int* off_ = (int*)(ws + 64);
  int* nwork = (int*)(ws + 128);
  int* wl = (int*)(ws + 256);              // <= 72 ints
  int* tok = (int*)(ws + 4096);
  float* gate = (float*)(ws + 4096 + (size_t)NEXP * CAP * 4);
  size_t HOFF = 4096 + 2 * (size_t)NEXP * CAP * 4;
  unsigned short* h = (unsigned short*)(ws + HOFF);
  size_t HSZ = (size_t)(16384 + 256) * DFF * 2;
  size_t XOFF = HOFF + HSZ;
  size_t WOFF = XOFF + (size_t)N_TOK * DMODEL * 2;
  size_t WSZ = (size_t)NEXP * DFF * DMODEL * 2;  // 64MB
  unsigned short* xb = (unsigned short*)(ws + XOFF);
  unsigned short* wT1 = (unsigned short*)(ws + WOFF);

  hipMemsetAsync(cnt, 0, 128, stream);
  hipMemsetAsync(out, 0, (size_t)out_size * 4, stream);
  router_k<<<N_TOK / 4, 256, 0, stream>>>(x, rw, cnt, tok, gate, xb);
  prefix_k<<<1, 64, 0, stream>>>(cnt, off_, nwork, wl);

  if (ws_size >= WOFF + 2 * WSZ) {
    unsigned short* wT2 = (unsigned short*)(ws + WOFF + WSZ);
    cvt_wt_k<<<NEXP * (DMODEL / 64) * (DFF / 64), 256, 0, stream>>>(wfc, wT1, DMODEL, DFF);
    cvt_wt_k<<<NEXP * (DFF / 64) * (DMODEL / 64), 256, 0, stream>>>(wproj, wT2, DFF, DMODEL);
    gemm1a_k<<<MAXW * NT1, 512, 0, stream>>>(xb, wT1, bfc, cnt, off_, tok, nwork, wl, h);
    gemm2a_k<<<MAXW * NT2, 512, 0, stream>>>(h, wT2, bproj, cnt, off_, tok, nwork, wl, gate, out);
  } else {
    cvt_wt_k<<<NEXP * (DMODEL / 64) * (DFF / 64), 256, 0, stream>>>(wfc, wT1, DMODEL, DFF);
    gemm1a_k<<<MAXW * NT1, 512, 0, stream>>>(xb, wT1, bfc, cnt, off_, tok, nwork, wl, h);
    cvt_wt_k<<<NEXP * (DFF / 64) * (DMODEL / 64), 256, 0, stream>>>(wproj, wT1, DFF, DMODEL);
    gemm2a_k<<<MAXW * NT2, 512, 0, stream>>>(h, wT1, bproj, cnt, off_, tok, nwork, wl, gate, out);
  }
}

// Round 12
// 757.817 us; speedup vs baseline: 1.3368x; 1.3265x over previous
//
#include <hip/hip_runtime.h>
#include <hip/hip_bf16.h>

// MoE MLP (top-2 of 8 experts), D=1024, FF=4096, 8192 tokens, fp32 in/out.
// R7-submission base (best measured: 768us, occ 62%): 128x128 tiles, BK=32,
// 8 waves (512 thr) each 64x32, 3-deep prefetch, counted vmcnt, 48KB LDS.
// R12 adds: (a) conflict-free (r>>1)&3 chunk-XOR swizzle (linear LDS dest +
// inverse-swizzled global src + swizzled read), (b) static-unrolled KLOOP.

#define N_TOK 8192
#define DMODEL 1024
#define NEXP 8
#define DFF 4096
#define CAP 8192
#define MAXW 136  // >= sum_e ceil(Me/128)

typedef __attribute__((ext_vector_type(8))) short short8;
typedef __attribute__((ext_vector_type(4))) float f32x4;

#define GLOAD_LDS16(g, l)                                              \
  __builtin_amdgcn_global_load_lds(                                    \
      (const __attribute__((address_space(1))) unsigned int*)(g),      \
      (__attribute__((address_space(3))) unsigned int*)(l), 16, 0, 0)

__device__ __forceinline__ unsigned short f2bf(float f) {
  unsigned u = __float_as_uint(f);
  return (unsigned short)((u + 0x7FFFu + ((u >> 16) & 1u)) >> 16);  // RNE
}

__device__ __forceinline__ float gelu_f(float v) {
  return 0.5f * v * (1.0f + erff(v * 0.70710678118654752f));
}

// ---------------- Router: 1 wave per token (+ x -> bf16 copy) ----------------
__global__ void router_k(const float* __restrict__ x, const float* __restrict__ rw,
                         int* __restrict__ cnt, int* __restrict__ tok,
                         float* __restrict__ gate, unsigned short* __restrict__ xb) {
  int lane = threadIdx.x & 63;
  int t = blockIdx.x * 4 + (threadIdx.x >> 6);
  const float* xr = x + (size_t)t * DMODEL;
  unsigned short* xbr = xb + (size_t)t * DMODEL;
  float p[8];
#pragma unroll
  for (int e = 0; e < 8; ++e) p[e] = 0.0f;
#pragma unroll
  for (int j = 0; j < DMODEL / 64; ++j) {
    int i = lane + j * 64;
    float xv = xr[i];
    xbr[i] = f2bf(xv);
    const float4* r = (const float4*)(rw + (size_t)i * 8);
    float4 a = r[0], b = r[1];
    p[0] += xv * a.x; p[1] += xv * a.y; p[2] += xv * a.z; p[3] += xv * a.w;
    p[4] += xv * b.x; p[5] += xv * b.y; p[6] += xv * b.z; p[7] += xv * b.w;
  }
#pragma unroll
  for (int e = 0; e < 8; ++e) {
#pragma unroll
    for (int off = 32; off; off >>= 1) p[e] += __shfl_xor(p[e], off, 64);
  }
  if (lane == 0) {
    int e1 = 0;
#pragma unroll
    for (int e = 1; e < 8; ++e) if (p[e] > p[e1]) e1 = e;
    int e2 = (e1 == 0) ? 1 : 0;
#pragma unroll
    for (int e = 0; e < 8; ++e) if (e != e1 && p[e] > p[e2]) e2 = e;
    float w1 = 1.0f / (1.0f + expf(p[e2] - p[e1]));
    float w2 = 1.0f - w1;
    int s1 = atomicAdd(&cnt[e1], 1);
    tok[e1 * CAP + s1] = t; gate[e1 * CAP + s1] = w1;
    int s2 = atomicAdd(&cnt[e2], 1);
    tok[e2 * CAP + s2] = t; gate[e2 * CAP + s2] = w2;
  }
}

// prefix sums + compact worklist of (expert, 128-row m-tile) pairs
__global__ void prefix_k(const int* __restrict__ cnt, int* __restrict__ off,
                         int* __restrict__ nwork, int* __restrict__ wl) {
  if (threadIdx.x == 0 && blockIdx.x == 0) {
    int s = 0, n = 0;
    for (int e = 0; e < NEXP; ++e) {
      off[e] = s;
      int ntile = (cnt[e] + 127) >> 7;
      for (int mt = 0; mt < ntile; ++mt) wl[n++] = (e << 16) | mt;
      s += cnt[e];
    }
    nwork[0] = n;
  }
}

// W [E][K][N] fp32 -> WT [E][N][K] bf16 (64x64 tile LDS transpose)
__global__ __launch_bounds__(256) void cvt_wt_k(const float* __restrict__ W,
                                                unsigned short* __restrict__ WT,
                                                int K, int N) {
  __shared__ float ls[64][68];
  int b = blockIdx.x;
  int nkt = K >> 6, nnt = N >> 6;
  int kt = b % nkt;
  int nt = (b / nkt) % nnt;
  int e = b / (nkt * nnt);
  const float* Wb = W + (size_t)e * K * N + (size_t)(kt * 64) * N + nt * 64;
  int t = threadIdx.x;
  int nn = (t & 15) * 4, kr = t >> 4;
#pragma unroll
  for (int i = 0; i < 4; ++i) {
    float4 v = *(const float4*)(Wb + (size_t)(kr + 16 * i) * N + nn);
    *(float4*)&ls[kr + 16 * i][nn] = v;
  }
  __syncthreads();
  int on = t >> 2, kc = (t & 3) * 16;
  unsigned short* dst = WT + (size_t)e * N * K + (size_t)(nt * 64 + on) * K + kt * 64 + kc;
  short8 r0, r1;
#pragma unroll
  for (int j = 0; j < 8; ++j) r0[j] = (short)f2bf(ls[kc + j][on]);
#pragma unroll
  for (int j = 0; j < 8; ++j) r1[j] = (short)f2bf(ls[kc + 8 + j][on]);
  *(short8*)dst = r0;
  *(short8*)(dst + 8) = r1;
}

// ---- 128x128/BK32 GEMM core, conflict-free chunk swizzle ----
// Staging: thread t -> row r = t>>2 (0..127), physical 16B-chunk p = t&3.
// LDS dest linear: t*8 shorts (wave-uniform base + lane*16B). Logical chunk
// stored at p is p ^ ((r>>1)&3) -> global src k-offset lc pre-XORed.
// Read: logical chunk g at row -> physical (g ^ ((row>>1)&3)); for all
// fragment rows, (row>>1)&3 == (fr>>1)&3 (row bases are multiples of 8).
// 8-lane phase check: lanes fr=0..7 -> (parity, pc) all distinct -> 8 quads.
#define STAGE(buf, kk)                                          \
  do {                                                          \
    GLOAD_LDS16(gA + (kk), &As[buf][tid * 8]);                  \
    GLOAD_LDS16(gB + (kk), &Bs[buf][tid * 8]);                  \
  } while (0)

// 8 waves: wave w -> rows [(w>>2)*64, +64), cols [(w&3)*32, +32).
#define COMPUTE(buf)                                                            \
  do {                                                                          \
    short8 af[4], bfv[2];                                                       \
    _Pragma("unroll") for (int i = 0; i < 4; ++i)                               \
        af[i] = *(const short8*)&As[buf][(wr * 64 + i * 16 + fr) * 32 + co];    \
    _Pragma("unroll") for (int i = 0; i < 2; ++i)                               \
        bfv[i] = *(const short8*)&Bs[buf][(wc * 32 + i * 16 + fr) * 32 + co];   \
    _Pragma("unroll") for (int mi = 0; mi < 4; ++mi)                            \
        _Pragma("unroll") for (int ni = 0; ni < 2; ++ni)                        \
            acc[mi][ni] = __builtin_amdgcn_mfma_f32_16x16x32_bf16(              \
                af[mi], bfv[ni], acc[mi][ni], 0, 0, 0);                         \
  } while (0)

#define WAITV(n) asm volatile("s_waitcnt vmcnt(" #n ")" ::: "memory")
#define BAR() __builtin_amdgcn_s_barrier()

// 3-deep prefetch, counted vmcnt, STATIC buffer indices (triple unroll).
// 2 loads/thread/tile; steady outstanding 6; WAITV(4) retires current tile.
// Requires (KTOT/32 - 5) % 3 == 0 (true for 1024: 27/3, 4096: 123/3).
#define KLOOP(KTOT)                                                       \
  STAGE(0, 0);                                                            \
  STAGE(1, 32);                                                           \
  STAGE(2, 64);                                                           \
  {                                                                       \
    int k0 = 0;                                                           \
    _Pragma("unroll 1") for (int it = 0; it < ((KTOT) / 32 - 5) / 3; ++it) { \
      WAITV(4); BAR(); COMPUTE(0); BAR(); STAGE(0, k0 + 96);              \
      WAITV(4); BAR(); COMPUTE(1); BAR(); STAGE(1, k0 + 128);             \
      WAITV(4); BAR(); COMPUTE(2); BAR(); STAGE(2, k0 + 160);             \
      k0 += 96;                                                           \
    }                                                                     \
    WAITV(4); BAR(); COMPUTE(0); BAR(); STAGE(0, k0 + 96);                \
    WAITV(4); BAR(); COMPUTE(1); BAR(); STAGE(1, k0 + 128);               \
    WAITV(4); BAR(); COMPUTE(2);                                          \
    WAITV(2); BAR(); COMPUTE(0);                                          \
    WAITV(0); BAR(); COMPUTE(1);                                          \
  }

// ---------------- GEMM1: h = gelu(Xb_gathered @ wfcT + bfc) ----------------
#define NT1 32
__global__ __launch_bounds__(512, 4) void gemm1a_k(
    const unsigned short* __restrict__ xb, const unsigned short* __restrict__ wT,
    const float* __restrict__ bfc, const int* __restrict__ cnt,
    const int* __restrict__ off, const int* __restrict__ tok,
    const int* __restrict__ nwork, const int* __restrict__ wl,
    unsigned short* __restrict__ h) {
  int bid = (int)(blockIdx.x & 7) * ((int)gridDim.x >> 3) + (int)(blockIdx.x >> 3);
  int widx = bid / NT1;   // slow: XCD chunk covers few widx x all nt
  int nt = bid % NT1;     // fast: neighbor blocks share the A-panel
  if (widx >= nwork[0]) return;
  int wle = wl[widx];
  int e = wle >> 16;
  int mt = wle & 0xffff;
  int Me = cnt[e];
  int base = off[e];
  int n0 = nt * 128;

  __shared__ __align__(16) unsigned short As[3][128 * 32];
  __shared__ __align__(16) unsigned short Bs[3][128 * 32];

  int tid = threadIdx.x;
  int lane = tid & 63, w = tid >> 6;
  int lc = (((tid & 3) ^ ((tid >> 3) & 3)) * 8);  // swizzled global k-offset

  int ari = mt * 128 + (tid >> 2);
  int t0 = tok[e * CAP + ((ari < Me) ? ari : (Me - 1))];
  const unsigned short* gA = xb + (size_t)t0 * DMODEL + lc;
  const unsigned short* gB = wT + ((size_t)e * DFF + n0 + (tid >> 2)) * DMODEL + lc;

  int wr = w >> 2, wc = w & 3;
  int g = lane >> 4, fr = lane & 15;
  int co = ((g ^ ((fr >> 1) & 3)) & 3) * 8;       // swizzled read chunk

  f32x4 acc[4][2];
#pragma unroll
  for (int i = 0; i < 4; ++i)
#pragma unroll
    for (int j = 0; j < 2; ++j) acc[i][j] = (f32x4)0.0f;

  KLOOP(DMODEL);

#pragma unroll
  for (int mi = 0; mi < 4; ++mi) {
    int rl = wr * 64 + mi * 16 + g * 4;
#pragma unroll
    for (int i = 0; i < 4; ++i) {
      int r = mt * 128 + rl + i;
      if (r < Me) {
        unsigned short* hrow = h + (size_t)(base + r) * DFF;
#pragma unroll
        for (int ni = 0; ni < 2; ++ni) {
          int col = n0 + wc * 32 + ni * 16 + fr;
          float v = acc[mi][ni][i] + bfc[e * DFF + col];
          hrow[col] = f2bf(gelu_f(v));
        }
      }
    }
  }
}

// ---------------- GEMM2: out += gate * (h @ wprojT + bproj) ----------------
#define NT2 8
__global__ __launch_bounds__(512, 4) void gemm2a_k(
    const unsigned short* __restrict__ h, const unsigned short* __restrict__ wT,
    const float* __restrict__ bproj, const int* __restrict__ cnt,
    const int* __restrict__ off, const int* __restrict__ tok,
    const int* __restrict__ nwork, const int* __restrict__ wl,
    const float* __restrict__ gate, float* __restrict__ out) {
  int bid = (int)(blockIdx.x & 7) * ((int)gridDim.x >> 3) + (int)(blockIdx.x >> 3);
  int widx = bid / NT2;
  int nt = bid % NT2;
  if (widx >= nwork[0]) return;
  int wle = wl[widx];
  int e = wle >> 16;
  int mt = wle & 0xffff;
  int Me = cnt[e];
  int base = off[e];
  int n0 = nt * 128;

  __shared__ __align__(16) unsigned short As[3][128 * 32];
  __shared__ __align__(16) unsigned short Bs[3][128 * 32];

  int tid = threadIdx.x;
  int lane = tid & 63, w = tid >> 6;
  int lc = (((tid & 3) ^ ((tid >> 3) & 3)) * 8);

  // A rows beyond Me read following rows (in-bounds: h padded +128); masked at store.
  const unsigned short* gA = h + (size_t)(base + mt * 128 + (tid >> 2)) * DFF + lc;
  const unsigned short* gB = wT + ((size_t)e * DMODEL + n0 + (tid >> 2)) * DFF + lc;

  int wr = w >> 2, wc = w & 3;
  int g = lane >> 4, fr = lane & 15;
  int co = ((g ^ ((fr >> 1) & 3)) & 3) * 8;

  f32x4 acc[4][2];
#pragma unroll
  for (int i = 0; i < 4; ++i)
#pragma unroll
    for (int j = 0; j < 2; ++j) acc[i][j] = (f32x4)0.0f;

  KLOOP(DFF);

#pragma unroll
  for (int mi = 0; mi < 4; ++mi) {
    int rl = wr * 64 + mi * 16 + g * 4;
#pragma unroll
    for (int i = 0; i < 4; ++i) {
      int r = mt * 128 + rl + i;
      if (r < Me) {
        int tkn = tok[e * CAP + r];
        float gv = gate[e * CAP + r];
        float* orow = out + (size_t)tkn * DMODEL;
#pragma unroll
        for (int ni = 0; ni < 2; ++ni) {
          int col = n0 + wc * 32 + ni * 16 + fr;
          float v = acc[mi][ni][i] + bproj[e * DMODEL + col];
          atomicAdd(orow + col, gv * v);
        }
      }
    }
  }
}

extern "C" void kernel_launch(void* const* d_in, const int* in_sizes, int n_in,
                              void* d_out, int out_size, void* d_ws, size_t ws_size,
                              hipStream_t stream) {
  const float* x = (const float*)d_in[0];
  const float* rw = (const float*)d_in[1];
  const float* wfc = (const float*)d_in[2];
  const float* bfc = (const float*)d_in[3];
  const float* wproj = (const float*)d_in[4];
  const float* bproj = (const float*)d_in[5];
  float* out = (float*)d_out;

  char* ws = (char*)d_ws;
  int* cnt = (int*)ws;
  int* off_ = (int*)(ws + 64);
  int* nwork = (int*)(ws + 128);
  int* wl = (int*)(ws + 256);              // <= 136 ints
  int* tok = (int*)(ws + 4096);
  float* gate = (float*)(ws + 4096 + (size_t)NEXP * CAP * 4);
  size_t HOFF = 4096 + 2 * (size_t)NEXP * CAP * 4;
  unsigned short* h = (unsigned short*)(ws + HOFF);
  size_t HSZ = (size_t)(16384 + 128) * DFF * 2;
  size_t XOFF = HOFF + HSZ;
  size_t WOFF = XOFF + (size_t)N_TOK * DMODEL * 2;
  size_t WSZ = (size_t)NEXP * DFF * DMODEL * 2;  // 64MB
  unsigned short* xb = (unsigned short*)(ws + XOFF);
  unsigned short* wT1 = (unsigned short*)(ws + WOFF);

  hipMemsetAsync(cnt, 0, 128, stream);
  hipMemsetAsync(out, 0, (size_t)out_size * 4, stream);
  router_k<<<N_TOK / 4, 256, 0, stream>>>(x, rw, cnt, tok, gate, xb);
  prefix_k<<<1, 64, 0, stream>>>(cnt, off_, nwork, wl);

  if (ws_size >= WOFF + 2 * WSZ) {
    // two weight buffers: both converts up-front, h stays L3-warm into gemm2
    unsigned short* wT2 = (unsigned short*)(ws + WOFF + WSZ);
    cvt_wt_k<<<NEXP * (DMODEL / 64) * (DFF / 64), 256, 0, stream>>>(wfc, wT1, DMODEL, DFF);
    cvt_wt_k<<<NEXP * (DFF / 64) * (DMODEL / 64), 256, 0, stream>>>(wproj, wT2, DFF, DMODEL);
    gemm1a_k<<<MAXW * NT1, 512, 0, stream>>>(xb, wT1, bfc, cnt, off_, tok, nwork, wl, h);
    gemm2a_k<<<MAXW * NT2, 512, 0, stream>>>(h, wT2, bproj, cnt, off_, tok, nwork, wl, gate, out);
  } else {
    cvt_wt_k<<<NEXP * (DMODEL / 64) * (DFF / 64), 256, 0, stream>>>(wfc, wT1, DMODEL, DFF);
    gemm1a_k<<<MAXW * NT1, 512, 0, stream>>>(xb, wT1, bfc, cnt, off_, tok, nwork, wl, h);
    cvt_wt_k<<<NEXP * (DFF / 64) * (DMODEL / 64), 256, 0, stream>>>(wproj, wT1, DFF, DMODEL);
    gemm2a_k<<<MAXW * NT2, 512, 0, stream>>>(h, wT1, bproj, cnt, off_, tok, nwork, wl, gate, out);
  }
}